// Round 5
// baseline (127.090 us; speedup 1.0000x reference)
//
#include <hip/hip_runtime.h>
#include <hip/hip_bf16.h>

#define NN 4096      // N = 2*B
#define BB 2048      // B
#define DD 512       // D
#define TM 128       // C tile (M and N)
#define BK 64        // K tile
#define NTILE (NN/TM)                 // 32
#define NPAIR (NTILE*(NTILE+1)/2)     // 528 blocks: bi <= bj

typedef __bf16 bf16x8 __attribute__((ext_vector_type(8)));
typedef float  f32x4  __attribute__((ext_vector_type(4)));

// async global->LDS, 16B per lane. LDS dest must be wave-uniform base + lane*16.
#define GLOAD_LDS16(gsrc, ldst)                                                  \
    __builtin_amdgcn_global_load_lds(                                            \
        (__attribute__((address_space(1))) void*)(gsrc),                         \
        (__attribute__((address_space(3))) void*)(ldst), 16, 0, 0)

__device__ __forceinline__ unsigned short f2bf(float x) {
    unsigned int u = __float_as_uint(x);
    unsigned int r = (u + 0x7fffu + ((u >> 16) & 1u)) >> 16;  // RNE; inputs finite
    return (unsigned short)r;
}

// ---------------------------------------------------------------------------
// Kernel A: row-normalize z = [z_i; z_j] -> bf16 zn[N][D]; zero-inits
// rowsum[] and the completion counter (kernel-boundary ordering makes these
// visible to Kernel B).
// ---------------------------------------------------------------------------
__global__ __launch_bounds__(256) void normalize_kernel(
        const float* __restrict__ z_i, const float* __restrict__ z_j,
        unsigned short* __restrict__ zn, float* __restrict__ rowsum,
        unsigned int* __restrict__ counter) {
    if (threadIdx.x < 4) rowsum[blockIdx.x * 4 + threadIdx.x] = 0.f;
    if (blockIdx.x == 0 && threadIdx.x == 0) *counter = 0u;

    int row  = blockIdx.x * 4 + (threadIdx.x >> 6);
    int lane = threadIdx.x & 63;
    const float* src = (row < BB) ? (z_i + (size_t)row * DD)
                                  : (z_j + (size_t)(row - BB) * DD);
    const float4* s4 = (const float4*)src;
    float4 v0 = s4[lane * 2 + 0];
    float4 v1 = s4[lane * 2 + 1];
    float ss = v0.x*v0.x + v0.y*v0.y + v0.z*v0.z + v0.w*v0.w
             + v1.x*v1.x + v1.y*v1.y + v1.z*v1.z + v1.w*v1.w;
    #pragma unroll
    for (int off = 1; off < 64; off <<= 1) ss += __shfl_xor(ss, off, 64);
    float inv = 1.0f / fmaxf(sqrtf(ss), 1e-8f);

    float f[8] = {v0.x, v0.y, v0.z, v0.w, v1.x, v1.y, v1.z, v1.w};
    unsigned int p[4];
    #pragma unroll
    for (int k = 0; k < 4; ++k) {
        unsigned int lo = f2bf(f[2*k] * inv);
        unsigned int hi = f2bf(f[2*k+1] * inv);
        p[k] = lo | (hi << 16);
    }
    uint4 outv = make_uint4(p[0], p[1], p[2], p[3]);
    *(uint4*)(zn + (size_t)row * DD + lane * 8) = outv;
}

// ---------------------------------------------------------------------------
// Kernel B: sim = (zn @ zn^T) * 2, upper-triangular tiles only (bi <= bj).
// rowsum[r] += sum_j exp(sim[r][j]) via row-sums + (off-diag) col-sums.
// Extracts selfsim (diag tiles) and possim (bj==bi+16 tiles).
// TAIL: rocPRIM-style "last block" — device-scope counter; the final block
// to finish performs the whole loss reduction and plain-stores out[0].
// (No co-residency / dispatch-order assumption: nothing spins.)
// ---------------------------------------------------------------------------
__global__ __launch_bounds__(256) void simexp_kernel(
        const unsigned short* __restrict__ zn, float* __restrict__ rowsum,
        float* __restrict__ selfsim, float* __restrict__ possim,
        unsigned int* __restrict__ counter, float* __restrict__ out) {
    __shared__ __align__(16) unsigned short As[TM * BK];
    __shared__ __align__(16) unsigned short Bs[TM * BK];
    __shared__ bool amLast;

    // triangular decode: p -> (bi <= bj)
    int p  = blockIdx.x;
    int bj = (int)((sqrtf(8.0f * (float)p + 1.0f) - 1.0f) * 0.5f);
    while ((bj + 1) * (bj + 2) / 2 <= p) ++bj;
    while (bj * (bj + 1) / 2 > p) --bj;
    int bi = p - bj * (bj + 1) / 2;
    const bool diag = (bi == bj);

    const int tid  = threadIdx.x;
    const int wave = tid >> 6, lane = tid & 63;
    const int wr = wave >> 1, wc = wave & 1;   // 2x2 wave grid, 64x64 each
    const int lrow = lane & 15, quad = lane >> 4;

    f32x4 acc[4][4];
    #pragma unroll
    for (int i = 0; i < 4; ++i)
        #pragma unroll
        for (int j = 0; j < 4; ++j) acc[i][j] = (f32x4){0.f, 0.f, 0.f, 0.f};

    const unsigned short* Bsrc = diag ? As : Bs;   // diag tiles reuse As

    for (int kb = 0; kb < DD; kb += BK) {
        __syncthreads();   // protect LDS from previous iter's readers
        #pragma unroll
        for (int it = 0; it < 4; ++it) {
            int t  = it * 256 + tid;       // chunk-slot 0..1023
            int r  = t >> 3;               // tile row 0..127
            int cc = t & 7;                // LDS chunk slot
            int sc = cc ^ (r & 7);         // global source chunk (swizzle)
            GLOAD_LDS16(zn + (size_t)(bi * TM + r) * DD + kb + sc * 8, As + t * 8);
            if (!diag)
                GLOAD_LDS16(zn + (size_t)(bj * TM + r) * DD + kb + sc * 8, Bs + t * 8);
        }
        __syncthreads();   // drains vmcnt(0) before LDS reads

        #pragma unroll
        for (int s = 0; s < 2; ++s) {      // two K=32 steps per BK=64
            bf16x8 a[4], b[4];
            #pragma unroll
            for (int ti = 0; ti < 4; ++ti) {
                int m = wr * 64 + ti * 16 + lrow;
                int q = (s * 4 + quad) ^ (m & 7);
                a[ti] = *(const bf16x8*)&As[m * BK + q * 8];
            }
            #pragma unroll
            for (int tj = 0; tj < 4; ++tj) {
                int n = wc * 64 + tj * 16 + lrow;
                int q = (s * 4 + quad) ^ (n & 7);
                b[tj] = *(const bf16x8*)&Bsrc[n * BK + q * 8];
            }
            #pragma unroll
            for (int ti = 0; ti < 4; ++ti)
                #pragma unroll
                for (int tj = 0; tj < 4; ++tj)
                    acc[ti][tj] = __builtin_amdgcn_mfma_f32_16x16x32_bf16(
                        a[ti], b[tj], acc[ti][tj], 0, 0, 0);
        }
    }

    // Epilogue. C/D layout (verified, absmax 0.0 in R0-R2):
    //   tile row = wr*64 + ti*16 + quad*4 + reg, tile col = wc*64 + tj*16 + lrow
    float rowpart[4][4];   // [ti][reg]
    float colpart[4];      // [tj]
    #pragma unroll
    for (int i = 0; i < 4; ++i) {
        colpart[i] = 0.f;
        #pragma unroll
        for (int r = 0; r < 4; ++r) rowpart[i][r] = 0.f;
    }
    #pragma unroll
    for (int ti = 0; ti < 4; ++ti)
        #pragma unroll
        for (int tj = 0; tj < 4; ++tj)
            #pragma unroll
            for (int reg = 0; reg < 4; ++reg) {
                float e = __expf(acc[ti][tj][reg] * 2.0f);
                rowpart[ti][reg] += e;
                colpart[tj]      += e;
            }

    // row-sums: reduce over lrow (16-lane groups)
    #pragma unroll
    for (int ti = 0; ti < 4; ++ti) {
        #pragma unroll
        for (int reg = 0; reg < 4; ++reg) {
            float v = rowpart[ti][reg];
            v += __shfl_xor(v, 1, 64);
            v += __shfl_xor(v, 2, 64);
            v += __shfl_xor(v, 4, 64);
            v += __shfl_xor(v, 8, 64);
            if (lrow == 0)
                atomicAdd(&rowsum[bi * TM + wr * 64 + ti * 16 + quad * 4 + reg], v);
        }
    }
    // col-sums -> rows of bj tile (transpose); skip on diagonal tiles
    if (!diag) {
        #pragma unroll
        for (int tj = 0; tj < 4; ++tj) {
            float v = colpart[tj];
            v += __shfl_xor(v, 16, 64);
            v += __shfl_xor(v, 32, 64);
            if (quad == 0)
                atomicAdd(&rowsum[bj * TM + wc * 64 + tj * 16 + lrow], v);
        }
    }

    // tile-diagonal extraction: lanes lrow>>2==quad in waves wr==wc hold
    // element (r, r) of the tile at acc[ti][ti][lrow&3], r = wr*64+ti*16+lrow.
    const bool posb = (bj == bi + NTILE / 2);   // bj == bi + 16  (col offset B)
    if ((diag || posb) && wr == wc && (lrow >> 2) == quad) {
        #pragma unroll
        for (int ti = 0; ti < 4; ++ti) {
            float v = 2.0f * acc[ti][ti][lrow & 3];
            int R = bi * TM + wr * 64 + ti * 16 + lrow;
            if (diag) {
                selfsim[R] = v;
            } else {
                possim[R]      = v;   // sim[r][r+B]
                possim[R + BB] = v;   // == sim[r+B][r]
            }
        }
    }

    // ---- last-block-finishes final reduction ----
    __threadfence();   // release: all rowsum/selfsim/possim writes visible
    if (tid == 0) {
        unsigned int prev = __hip_atomic_fetch_add(
            counter, 1u, __ATOMIC_ACQ_REL, __HIP_MEMORY_SCOPE_AGENT);
        amLast = (prev == NPAIR - 1);
    }
    __syncthreads();
    if (amLast) {
        __threadfence();   // acquire: see every block's writes
        float sum = 0.f;
        for (int r = tid; r < NN; r += 256) {
            float rs = __hip_atomic_load(&rowsum[r],  __ATOMIC_RELAXED,
                                         __HIP_MEMORY_SCOPE_AGENT);
            float ss = __hip_atomic_load(&selfsim[r], __ATOMIC_RELAXED,
                                         __HIP_MEMORY_SCOPE_AGENT);
            float ps = __hip_atomic_load(&possim[r],  __ATOMIC_RELAXED,
                                         __HIP_MEMORY_SCOPE_AGENT);
            sum += logf(rs - __expf(ss)) - ps;
        }
        #pragma unroll
        for (int off = 1; off < 64; off <<= 1) sum += __shfl_xor(sum, off, 64);
        float* s = (float*)As;   // LDS reuse; __syncthreads above ordered it
        if (lane == 0) s[wave] = sum;
        __syncthreads();
        if (tid == 0) out[0] = (s[0] + s[1] + s[2] + s[3]) * (1.0f / (float)NN);
    }
}

extern "C" void kernel_launch(void* const* d_in, const int* in_sizes, int n_in,
                              void* d_out, int out_size, void* d_ws, size_t ws_size,
                              hipStream_t stream) {
    const float* z_i = (const float*)d_in[0];
    const float* z_j = (const float*)d_in[1];
    float* out = (float*)d_out;

    unsigned short* zn = (unsigned short*)d_ws;                    // N*D bf16 = 4 MB
    float* rowsum  = (float*)((char*)d_ws + (size_t)NN * DD * 2);  // N floats
    float* selfsim = rowsum + NN;                                  // N floats
    float* possim  = selfsim + NN;                                 // N floats
    unsigned int* counter = (unsigned int*)(possim + NN);          // 1 u32

    normalize_kernel<<<NN / 4, 256, 0, stream>>>(z_i, z_j, zn, rowsum, counter);
    simexp_kernel<<<NPAIR, 256, 0, stream>>>(zn, rowsum, selfsim, possim,
                                             counter, out);
}

// Round 6
// 92.646 us; speedup vs baseline: 1.3718x; 1.3718x over previous
//
#include <hip/hip_runtime.h>
#include <hip/hip_bf16.h>

#define NN 4096      // N = 2*B
#define BB 2048      // B
#define DD 512       // D
#define TM 128       // C tile (M and N)
#define BK 64        // K tile
#define NTILE (NN/TM)                 // 32
#define NPAIR (NTILE*(NTILE+1)/2)     // 528 blocks: bi <= bj

typedef __bf16 bf16x8 __attribute__((ext_vector_type(8)));
typedef float  f32x4  __attribute__((ext_vector_type(4)));

// async global->LDS, 16B per lane. LDS dest must be wave-uniform base + lane*16.
#define GLOAD_LDS16(gsrc, ldst)                                                  \
    __builtin_amdgcn_global_load_lds(                                            \
        (__attribute__((address_space(1))) void*)(gsrc),                         \
        (__attribute__((address_space(3))) void*)(ldst), 16, 0, 0)

__device__ __forceinline__ unsigned short f2bf(float x) {
    unsigned int u = __float_as_uint(x);
    unsigned int r = (u + 0x7fffu + ((u >> 16) & 1u)) >> 16;  // RNE; inputs finite
    return (unsigned short)r;
}

// ---------------------------------------------------------------------------
// Kernel A: row-normalize z = [z_i; z_j] -> bf16 zn[N][D]; zero-inits
// rowsum[] and the completion counter (kernel-boundary ordering makes these
// visible to Kernel B).
// ---------------------------------------------------------------------------
__global__ __launch_bounds__(256) void normalize_kernel(
        const float* __restrict__ z_i, const float* __restrict__ z_j,
        unsigned short* __restrict__ zn, float* __restrict__ rowsum,
        unsigned int* __restrict__ counter) {
    if (threadIdx.x < 4) rowsum[blockIdx.x * 4 + threadIdx.x] = 0.f;
    if (blockIdx.x == 0 && threadIdx.x == 0) *counter = 0u;

    int row  = blockIdx.x * 4 + (threadIdx.x >> 6);
    int lane = threadIdx.x & 63;
    const float* src = (row < BB) ? (z_i + (size_t)row * DD)
                                  : (z_j + (size_t)(row - BB) * DD);
    const float4* s4 = (const float4*)src;
    float4 v0 = s4[lane * 2 + 0];
    float4 v1 = s4[lane * 2 + 1];
    float ss = v0.x*v0.x + v0.y*v0.y + v0.z*v0.z + v0.w*v0.w
             + v1.x*v1.x + v1.y*v1.y + v1.z*v1.z + v1.w*v1.w;
    #pragma unroll
    for (int off = 1; off < 64; off <<= 1) ss += __shfl_xor(ss, off, 64);
    float inv = 1.0f / fmaxf(sqrtf(ss), 1e-8f);

    float f[8] = {v0.x, v0.y, v0.z, v0.w, v1.x, v1.y, v1.z, v1.w};
    unsigned int p[4];
    #pragma unroll
    for (int k = 0; k < 4; ++k) {
        unsigned int lo = f2bf(f[2*k] * inv);
        unsigned int hi = f2bf(f[2*k+1] * inv);
        p[k] = lo | (hi << 16);
    }
    uint4 outv = make_uint4(p[0], p[1], p[2], p[3]);
    *(uint4*)(zn + (size_t)row * DD + lane * 8) = outv;
}

// ---------------------------------------------------------------------------
// Kernel B: sim = (zn @ zn^T) * 2, upper-triangular tiles only (bi <= bj).
// rowsum[r] += sum_j exp(sim[r][j]) via row-sums + (off-diag) col-sums.
// Extracts selfsim (diag tiles) and possim (bj==bi+16 tiles).
// TAIL (fence-free): all cross-block data rides the coherence point —
// rowsum via plain atomicAdd (device-scope), selfsim/possim via RELAXED
// agent-scope atomic stores. __syncthreads() drains vmcnt before the
// RELAXED agent-scope counter bump (compiler emits s_waitcnt vmcnt(0)
// before s_barrier), so everything is committed before the count is
// visible. NO __threadfence / ACQ_REL: those emit buffer_wbl2/buffer_inv
// (L2 writeback-invalidate) on gfx950 — measured +50 µs in R4.
// ---------------------------------------------------------------------------
__global__ __launch_bounds__(256) void simexp_kernel(
        const unsigned short* __restrict__ zn, float* __restrict__ rowsum,
        float* __restrict__ selfsim, float* __restrict__ possim,
        unsigned int* __restrict__ counter, float* __restrict__ out) {
    __shared__ __align__(16) unsigned short As[TM * BK];
    __shared__ __align__(16) unsigned short Bs[TM * BK];
    __shared__ bool amLast;

    // triangular decode: p -> (bi <= bj)
    int p  = blockIdx.x;
    int bj = (int)((sqrtf(8.0f * (float)p + 1.0f) - 1.0f) * 0.5f);
    while ((bj + 1) * (bj + 2) / 2 <= p) ++bj;
    while (bj * (bj + 1) / 2 > p) --bj;
    int bi = p - bj * (bj + 1) / 2;
    const bool diag = (bi == bj);

    const int tid  = threadIdx.x;
    const int wave = tid >> 6, lane = tid & 63;
    const int wr = wave >> 1, wc = wave & 1;   // 2x2 wave grid, 64x64 each
    const int lrow = lane & 15, quad = lane >> 4;

    f32x4 acc[4][4];
    #pragma unroll
    for (int i = 0; i < 4; ++i)
        #pragma unroll
        for (int j = 0; j < 4; ++j) acc[i][j] = (f32x4){0.f, 0.f, 0.f, 0.f};

    const unsigned short* Bsrc = diag ? As : Bs;   // diag tiles reuse As

    for (int kb = 0; kb < DD; kb += BK) {
        __syncthreads();   // protect LDS from previous iter's readers
        #pragma unroll
        for (int it = 0; it < 4; ++it) {
            int t  = it * 256 + tid;       // chunk-slot 0..1023
            int r  = t >> 3;               // tile row 0..127
            int cc = t & 7;                // LDS chunk slot
            int sc = cc ^ (r & 7);         // global source chunk (swizzle)
            GLOAD_LDS16(zn + (size_t)(bi * TM + r) * DD + kb + sc * 8, As + t * 8);
            if (!diag)
                GLOAD_LDS16(zn + (size_t)(bj * TM + r) * DD + kb + sc * 8, Bs + t * 8);
        }
        __syncthreads();   // drains vmcnt(0) before LDS reads

        #pragma unroll
        for (int s = 0; s < 2; ++s) {      // two K=32 steps per BK=64
            bf16x8 a[4], b[4];
            #pragma unroll
            for (int ti = 0; ti < 4; ++ti) {
                int m = wr * 64 + ti * 16 + lrow;
                int q = (s * 4 + quad) ^ (m & 7);
                a[ti] = *(const bf16x8*)&As[m * BK + q * 8];
            }
            #pragma unroll
            for (int tj = 0; tj < 4; ++tj) {
                int n = wc * 64 + tj * 16 + lrow;
                int q = (s * 4 + quad) ^ (n & 7);
                b[tj] = *(const bf16x8*)&Bsrc[n * BK + q * 8];
            }
            #pragma unroll
            for (int ti = 0; ti < 4; ++ti)
                #pragma unroll
                for (int tj = 0; tj < 4; ++tj)
                    acc[ti][tj] = __builtin_amdgcn_mfma_f32_16x16x32_bf16(
                        a[ti], b[tj], acc[ti][tj], 0, 0, 0);
        }
    }

    // Epilogue. C/D layout (verified, absmax 0.0 in R0-R2/R4):
    //   tile row = wr*64 + ti*16 + quad*4 + reg, tile col = wc*64 + tj*16 + lrow
    float rowpart[4][4];   // [ti][reg]
    float colpart[4];      // [tj]
    #pragma unroll
    for (int i = 0; i < 4; ++i) {
        colpart[i] = 0.f;
        #pragma unroll
        for (int r = 0; r < 4; ++r) rowpart[i][r] = 0.f;
    }
    #pragma unroll
    for (int ti = 0; ti < 4; ++ti)
        #pragma unroll
        for (int tj = 0; tj < 4; ++tj)
            #pragma unroll
            for (int reg = 0; reg < 4; ++reg) {
                float e = __expf(acc[ti][tj][reg] * 2.0f);
                rowpart[ti][reg] += e;
                colpart[tj]      += e;
            }

    // row-sums: reduce over lrow (16-lane groups)
    #pragma unroll
    for (int ti = 0; ti < 4; ++ti) {
        #pragma unroll
        for (int reg = 0; reg < 4; ++reg) {
            float v = rowpart[ti][reg];
            v += __shfl_xor(v, 1, 64);
            v += __shfl_xor(v, 2, 64);
            v += __shfl_xor(v, 4, 64);
            v += __shfl_xor(v, 8, 64);
            if (lrow == 0)
                atomicAdd(&rowsum[bi * TM + wr * 64 + ti * 16 + quad * 4 + reg], v);
        }
    }
    // col-sums -> rows of bj tile (transpose); skip on diagonal tiles
    if (!diag) {
        #pragma unroll
        for (int tj = 0; tj < 4; ++tj) {
            float v = colpart[tj];
            v += __shfl_xor(v, 16, 64);
            v += __shfl_xor(v, 32, 64);
            if (quad == 0)
                atomicAdd(&rowsum[bj * TM + wc * 64 + tj * 16 + lrow], v);
        }
    }

    // tile-diagonal extraction: lanes lrow>>2==quad in waves wr==wc hold
    // element (r, r) of the tile at acc[ti][ti][lrow&3], r = wr*64+ti*16+lrow.
    // Agent-scope relaxed stores: write-through to coherence point, no fence.
    const bool posb = (bj == bi + NTILE / 2);   // bj == bi + 16  (col offset B)
    if ((diag || posb) && wr == wc && (lrow >> 2) == quad) {
        #pragma unroll
        for (int ti = 0; ti < 4; ++ti) {
            float v = 2.0f * acc[ti][ti][lrow & 3];
            int R = bi * TM + wr * 64 + ti * 16 + lrow;
            if (diag) {
                __hip_atomic_store(&selfsim[R], v, __ATOMIC_RELAXED,
                                   __HIP_MEMORY_SCOPE_AGENT);
            } else {
                __hip_atomic_store(&possim[R], v, __ATOMIC_RELAXED,
                                   __HIP_MEMORY_SCOPE_AGENT);      // sim[r][r+B]
                __hip_atomic_store(&possim[R + BB], v, __ATOMIC_RELAXED,
                                   __HIP_MEMORY_SCOPE_AGENT);      // sim[r+B][r]
            }
        }
    }

    // ---- last-block-finishes final reduction (fence-free) ----
    // Barrier drains vmcnt(0): this block's coherence-point ops (atomicAdds +
    // agent-scope stores) are committed before the counter bump below.
    __syncthreads();
    if (tid == 0) {
        unsigned int prev = __hip_atomic_fetch_add(
            counter, 1u, __ATOMIC_RELAXED, __HIP_MEMORY_SCOPE_AGENT);
        amLast = (prev == NPAIR - 1);
    }
    __syncthreads();
    if (amLast) {
        float sum = 0.f;
        for (int r = tid; r < NN; r += 256) {
            float rs = __hip_atomic_load(&rowsum[r],  __ATOMIC_RELAXED,
                                         __HIP_MEMORY_SCOPE_AGENT);
            float ss = __hip_atomic_load(&selfsim[r], __ATOMIC_RELAXED,
                                         __HIP_MEMORY_SCOPE_AGENT);
            float ps = __hip_atomic_load(&possim[r],  __ATOMIC_RELAXED,
                                         __HIP_MEMORY_SCOPE_AGENT);
            sum += logf(rs - __expf(ss)) - ps;
        }
        #pragma unroll
        for (int off = 1; off < 64; off <<= 1) sum += __shfl_xor(sum, off, 64);
        float* s = (float*)As;   // LDS reuse; barriers above ordered it
        if (lane == 0) s[wave] = sum;
        __syncthreads();
        if (tid == 0) out[0] = (s[0] + s[1] + s[2] + s[3]) * (1.0f / (float)NN);
    }
}

extern "C" void kernel_launch(void* const* d_in, const int* in_sizes, int n_in,
                              void* d_out, int out_size, void* d_ws, size_t ws_size,
                              hipStream_t stream) {
    const float* z_i = (const float*)d_in[0];
    const float* z_j = (const float*)d_in[1];
    float* out = (float*)d_out;

    unsigned short* zn = (unsigned short*)d_ws;                    // N*D bf16 = 4 MB
    float* rowsum  = (float*)((char*)d_ws + (size_t)NN * DD * 2);  // N floats
    float* selfsim = rowsum + NN;                                  // N floats
    float* possim  = selfsim + NN;                                 // N floats
    unsigned int* counter = (unsigned int*)(possim + NN);          // 1 u32

    normalize_kernel<<<NN / 4, 256, 0, stream>>>(z_i, z_j, zn, rowsum, counter);
    simexp_kernel<<<NPAIR, 256, 0, stream>>>(zn, rowsum, selfsim, possim,
                                             counter, out);
}

// Round 7
// 88.875 us; speedup vs baseline: 1.4300x; 1.0424x over previous
//
#include <hip/hip_runtime.h>
#include <hip/hip_bf16.h>

#define NN 4096      // N = 2*B
#define BB 2048      // B
#define DD 512       // D
#define TM 128       // C tile (M and N)
#define BK 64        // K tile
#define NTILE (NN/TM)                 // 32
#define NPAIR (NTILE*(NTILE+1)/2)     // 528 blocks: bi <= bj
#define NFIN 16                       // finisher blocks (each: 256 rows)

typedef __bf16 bf16x8 __attribute__((ext_vector_type(8)));
typedef float  f32x4  __attribute__((ext_vector_type(4)));

// async global->LDS, 16B per lane. LDS dest must be wave-uniform base + lane*16.
#define GLOAD_LDS16(gsrc, ldst)                                                  \
    __builtin_amdgcn_global_load_lds(                                            \
        (__attribute__((address_space(1))) void*)(gsrc),                         \
        (__attribute__((address_space(3))) void*)(ldst), 16, 0, 0)

__device__ __forceinline__ unsigned short f2bf(float x) {
    unsigned int u = __float_as_uint(x);
    unsigned int r = (u + 0x7fffu + ((u >> 16) & 1u)) >> 16;  // RNE; inputs finite
    return (unsigned short)r;
}

// ---------------------------------------------------------------------------
// Kernel A: row-normalize z = [z_i; z_j] -> bf16 zn[N][D]; zero-inits
// rowsum[], out[0], and the completion counter (kernel-boundary ordering
// makes these visible to Kernel B).
// ---------------------------------------------------------------------------
__global__ __launch_bounds__(256) void normalize_kernel(
        const float* __restrict__ z_i, const float* __restrict__ z_j,
        unsigned short* __restrict__ zn, float* __restrict__ rowsum,
        unsigned int* __restrict__ counter, float* __restrict__ out) {
    if (threadIdx.x < 4) rowsum[blockIdx.x * 4 + threadIdx.x] = 0.f;
    if (blockIdx.x == 0 && threadIdx.x == 0) { *counter = 0u; out[0] = 0.f; }

    int row  = blockIdx.x * 4 + (threadIdx.x >> 6);
    int lane = threadIdx.x & 63;
    const float* src = (row < BB) ? (z_i + (size_t)row * DD)
                                  : (z_j + (size_t)(row - BB) * DD);
    const float4* s4 = (const float4*)src;
    float4 v0 = s4[lane * 2 + 0];
    float4 v1 = s4[lane * 2 + 1];
    float ss = v0.x*v0.x + v0.y*v0.y + v0.z*v0.z + v0.w*v0.w
             + v1.x*v1.x + v1.y*v1.y + v1.z*v1.z + v1.w*v1.w;
    #pragma unroll
    for (int off = 1; off < 64; off <<= 1) ss += __shfl_xor(ss, off, 64);
    float inv = 1.0f / fmaxf(sqrtf(ss), 1e-8f);

    float f[8] = {v0.x, v0.y, v0.z, v0.w, v1.x, v1.y, v1.z, v1.w};
    unsigned int p[4];
    #pragma unroll
    for (int k = 0; k < 4; ++k) {
        unsigned int lo = f2bf(f[2*k] * inv);
        unsigned int hi = f2bf(f[2*k+1] * inv);
        p[k] = lo | (hi << 16);
    }
    uint4 outv = make_uint4(p[0], p[1], p[2], p[3]);
    *(uint4*)(zn + (size_t)row * DD + lane * 8) = outv;
}

// ---------------------------------------------------------------------------
// Kernel B: sim = (zn @ zn^T) * 2, upper-triangular tiles only (bi <= bj).
// rowsum[r] += sum_j exp(sim[r][j]) via row-sums + (off-diag) col-sums.
// Extracts selfsim (diag tiles) and possim (bj==bi+16 tiles).
// TAIL (fence-free, R5-validated): all cross-block data rides the coherence
// point — rowsum via plain atomicAdd (device-scope), selfsim/possim via
// RELAXED agent-scope atomic stores; __syncthreads() drains vmcnt before the
// RELAXED agent-scope counter bump. NO __threadfence / ACQ_REL (those emit
// buffer_wbl2/buffer_inv on gfx950 — measured +50 µs in R4).
// NEW (R6): parallel finishers — the 16 highest-blockIdx blocks spin on the
// counter (relaxed agent load + s_sleep; deadlock-free: counter always
// reaches NPAIR since the main phase has no cross-block deps) and each
// reduces a 256-row slice -> atomicAdd(out). Replaces the single-last-block
// serial reduction (~48 uncached load rounds/lane with 255 CUs idle).
// ---------------------------------------------------------------------------
__global__ __launch_bounds__(256) void simexp_kernel(
        const unsigned short* __restrict__ zn, float* __restrict__ rowsum,
        float* __restrict__ selfsim, float* __restrict__ possim,
        unsigned int* __restrict__ counter, float* __restrict__ out) {
    __shared__ __align__(16) unsigned short As[TM * BK];
    __shared__ __align__(16) unsigned short Bs[TM * BK];

    // triangular decode: p -> (bi <= bj)
    int p  = blockIdx.x;
    int bj = (int)((sqrtf(8.0f * (float)p + 1.0f) - 1.0f) * 0.5f);
    while ((bj + 1) * (bj + 2) / 2 <= p) ++bj;
    while (bj * (bj + 1) / 2 > p) --bj;
    int bi = p - bj * (bj + 1) / 2;
    const bool diag = (bi == bj);

    const int tid  = threadIdx.x;
    const int wave = tid >> 6, lane = tid & 63;
    const int wr = wave >> 1, wc = wave & 1;   // 2x2 wave grid, 64x64 each
    const int lrow = lane & 15, quad = lane >> 4;

    f32x4 acc[4][4];
    #pragma unroll
    for (int i = 0; i < 4; ++i)
        #pragma unroll
        for (int j = 0; j < 4; ++j) acc[i][j] = (f32x4){0.f, 0.f, 0.f, 0.f};

    const unsigned short* Bsrc = diag ? As : Bs;   // diag tiles reuse As

    for (int kb = 0; kb < DD; kb += BK) {
        __syncthreads();   // protect LDS from previous iter's readers
        #pragma unroll
        for (int it = 0; it < 4; ++it) {
            int t  = it * 256 + tid;       // chunk-slot 0..1023
            int r  = t >> 3;               // tile row 0..127
            int cc = t & 7;                // LDS chunk slot
            int sc = cc ^ (r & 7);         // global source chunk (swizzle)
            GLOAD_LDS16(zn + (size_t)(bi * TM + r) * DD + kb + sc * 8, As + t * 8);
            if (!diag)
                GLOAD_LDS16(zn + (size_t)(bj * TM + r) * DD + kb + sc * 8, Bs + t * 8);
        }
        __syncthreads();   // drains vmcnt(0) before LDS reads

        #pragma unroll
        for (int s = 0; s < 2; ++s) {      // two K=32 steps per BK=64
            bf16x8 a[4], b[4];
            #pragma unroll
            for (int ti = 0; ti < 4; ++ti) {
                int m = wr * 64 + ti * 16 + lrow;
                int q = (s * 4 + quad) ^ (m & 7);
                a[ti] = *(const bf16x8*)&As[m * BK + q * 8];
            }
            #pragma unroll
            for (int tj = 0; tj < 4; ++tj) {
                int n = wc * 64 + tj * 16 + lrow;
                int q = (s * 4 + quad) ^ (n & 7);
                b[tj] = *(const bf16x8*)&Bsrc[n * BK + q * 8];
            }
            #pragma unroll
            for (int ti = 0; ti < 4; ++ti)
                #pragma unroll
                for (int tj = 0; tj < 4; ++tj)
                    acc[ti][tj] = __builtin_amdgcn_mfma_f32_16x16x32_bf16(
                        a[ti], b[tj], acc[ti][tj], 0, 0, 0);
        }
    }

    // Epilogue. C/D layout (verified, absmax 0.0 in R0-R2/R4/R5):
    //   tile row = wr*64 + ti*16 + quad*4 + reg, tile col = wc*64 + tj*16 + lrow
    float rowpart[4][4];   // [ti][reg]
    float colpart[4];      // [tj]
    #pragma unroll
    for (int i = 0; i < 4; ++i) {
        colpart[i] = 0.f;
        #pragma unroll
        for (int r = 0; r < 4; ++r) rowpart[i][r] = 0.f;
    }
    #pragma unroll
    for (int ti = 0; ti < 4; ++ti)
        #pragma unroll
        for (int tj = 0; tj < 4; ++tj)
            #pragma unroll
            for (int reg = 0; reg < 4; ++reg) {
                float e = __expf(acc[ti][tj][reg] * 2.0f);
                rowpart[ti][reg] += e;
                colpart[tj]      += e;
            }

    // row-sums: reduce over lrow (16-lane groups)
    #pragma unroll
    for (int ti = 0; ti < 4; ++ti) {
        #pragma unroll
        for (int reg = 0; reg < 4; ++reg) {
            float v = rowpart[ti][reg];
            v += __shfl_xor(v, 1, 64);
            v += __shfl_xor(v, 2, 64);
            v += __shfl_xor(v, 4, 64);
            v += __shfl_xor(v, 8, 64);
            if (lrow == 0)
                atomicAdd(&rowsum[bi * TM + wr * 64 + ti * 16 + quad * 4 + reg], v);
        }
    }
    // col-sums -> rows of bj tile (transpose); skip on diagonal tiles
    if (!diag) {
        #pragma unroll
        for (int tj = 0; tj < 4; ++tj) {
            float v = colpart[tj];
            v += __shfl_xor(v, 16, 64);
            v += __shfl_xor(v, 32, 64);
            if (quad == 0)
                atomicAdd(&rowsum[bj * TM + wc * 64 + tj * 16 + lrow], v);
        }
    }

    // tile-diagonal extraction: lanes lrow>>2==quad in waves wr==wc hold
    // element (r, r) of the tile at acc[ti][ti][lrow&3], r = wr*64+ti*16+lrow.
    // Agent-scope relaxed stores: write-through to coherence point, no fence.
    const bool posb = (bj == bi + NTILE / 2);   // bj == bi + 16  (col offset B)
    if ((diag || posb) && wr == wc && (lrow >> 2) == quad) {
        #pragma unroll
        for (int ti = 0; ti < 4; ++ti) {
            float v = 2.0f * acc[ti][ti][lrow & 3];
            int R = bi * TM + wr * 64 + ti * 16 + lrow;
            if (diag) {
                __hip_atomic_store(&selfsim[R], v, __ATOMIC_RELAXED,
                                   __HIP_MEMORY_SCOPE_AGENT);
            } else {
                __hip_atomic_store(&possim[R], v, __ATOMIC_RELAXED,
                                   __HIP_MEMORY_SCOPE_AGENT);      // sim[r][r+B]
                __hip_atomic_store(&possim[R + BB], v, __ATOMIC_RELAXED,
                                   __HIP_MEMORY_SCOPE_AGENT);      // sim[r+B][r]
            }
        }
    }

    // ---- completion counter (fence-free, R5-validated) ----
    // Barrier drains vmcnt(0): this block's coherence-point ops (atomicAdds +
    // agent-scope stores) are committed before the counter bump below.
    __syncthreads();
    if (tid == 0)
        __hip_atomic_fetch_add(counter, 1u, __ATOMIC_RELAXED,
                               __HIP_MEMORY_SCOPE_AGENT);

    // ---- parallel finishers: last NFIN blocks by blockIdx ----
    if (blockIdx.x >= NPAIR - NFIN) {
        if (tid == 0) {
            while (__hip_atomic_load(counter, __ATOMIC_RELAXED,
                                     __HIP_MEMORY_SCOPE_AGENT) < NPAIR)
                __builtin_amdgcn_s_sleep(8);
        }
        __syncthreads();   // release waiting waves once counter is full

        int r = (blockIdx.x - (NPAIR - NFIN)) * 256 + tid;   // 1 row per thread
        float rs = __hip_atomic_load(&rowsum[r],  __ATOMIC_RELAXED,
                                     __HIP_MEMORY_SCOPE_AGENT);
        float ss = __hip_atomic_load(&selfsim[r], __ATOMIC_RELAXED,
                                     __HIP_MEMORY_SCOPE_AGENT);
        float ps = __hip_atomic_load(&possim[r],  __ATOMIC_RELAXED,
                                     __HIP_MEMORY_SCOPE_AGENT);
        float v = logf(rs - __expf(ss)) - ps;
        #pragma unroll
        for (int off = 1; off < 64; off <<= 1) v += __shfl_xor(v, off, 64);
        float* s = (float*)As;   // LDS reuse; barrier above ordered it
        if (lane == 0) s[wave] = v;
        __syncthreads();
        if (tid == 0)
            atomicAdd(out, (s[0] + s[1] + s[2] + s[3]) * (1.0f / (float)NN));
    }
}

extern "C" void kernel_launch(void* const* d_in, const int* in_sizes, int n_in,
                              void* d_out, int out_size, void* d_ws, size_t ws_size,
                              hipStream_t stream) {
    const float* z_i = (const float*)d_in[0];
    const float* z_j = (const float*)d_in[1];
    float* out = (float*)d_out;

    unsigned short* zn = (unsigned short*)d_ws;                    // N*D bf16 = 4 MB
    float* rowsum  = (float*)((char*)d_ws + (size_t)NN * DD * 2);  // N floats
    float* selfsim = rowsum + NN;                                  // N floats
    float* possim  = selfsim + NN;                                 // N floats
    unsigned int* counter = (unsigned int*)(possim + NN);          // 1 u32

    normalize_kernel<<<NN / 4, 256, 0, stream>>>(z_i, z_j, zn, rowsum,
                                                 counter, out);
    simexp_kernel<<<NPAIR, 256, 0, stream>>>(zn, rowsum, selfsim, possim,
                                             counter, out);
}